// Round 1
// baseline (300.121 us; speedup 1.0000x reference)
//
#include <hip/hip_runtime.h>
#include <stdint.h>

#define B_ 2
#define T_ 2048
#define C_ 1024
#define H_ 16
#define DH_ 64
#define M_ (B_*T_)   // 4096

typedef short bhalf8 __attribute__((ext_vector_type(8)));
typedef float floatx4 __attribute__((ext_vector_type(4)));

__device__ __forceinline__ short f2bf(float f) {
  unsigned u = __float_as_uint(f);
  u += 0x7fffu + ((u >> 16) & 1u);   // round-to-nearest-even
  return (short)(u >> 16);
}

// async global->LDS, 16B per lane; lds_dst must be wave-uniform (lane data
// lands at lds_dst + lane*16)
__device__ __forceinline__ void gll16(void* lds_dst, const void* g_src) {
  __builtin_amdgcn_global_load_lds(
      reinterpret_cast<const uint32_t __attribute__((address_space(1)))*>(
          reinterpret_cast<uintptr_t>(g_src)),
      reinterpret_cast<uint32_t __attribute__((address_space(3)))*>(
          reinterpret_cast<uintptr_t>(lds_dst)),
      16, 0, 0);
}

__global__ void cvt_bf16(const float* __restrict__ src, short* __restrict__ dst, int n4) {
  int i = blockIdx.x * blockDim.x + threadIdx.x;
  if (i >= n4) return;
  float4 v = ((const float4*)src)[i];
  short4 o;
  o.x = f2bf(v.x); o.y = f2bf(v.y); o.z = f2bf(v.z); o.w = f2bf(v.w);
  ((short4*)dst)[i] = o;
}

// C = A(M x K) @ B^T where B is (N x K), both bf16 row-major, K = 1024.
// MODE 0: fp32 out, row-major (M x C_)   [final Wo projection]
// MODE 1: bf16 out, (B,H,T,DH) layout    [V]
// MODE 2: bf16 out, (B,H,T,DH) + RoPE    [Q, K]
template<int MODE>
__global__ __launch_bounds__(256) void gemm_bt(
    const short* __restrict__ A, const short* __restrict__ Bm,
    void* __restrict__ Cout)
{
  __shared__ __align__(16) short As[128*32];
  __shared__ __align__(16) short Bs[128*32];
  const int tid  = threadIdx.x;
  const int lane = tid & 63;
  const int wv   = tid >> 6;
  const int l15  = lane & 15;
  const int quad = lane >> 4;
  const int wm   = (wv >> 1) << 6;   // wave row offset (2x2 wave grid)
  const int wn   = (wv & 1) << 6;    // wave col offset (= one head for MODE 1/2)
  const int n0   = blockIdx.x << 7;
  const int m0   = blockIdx.y << 7;
  const int K    = C_;

  floatx4 acc[4][4] = {};

  const short* Ab = A  + (size_t)m0 * K;
  const short* Bb = Bm + (size_t)n0 * K;

  for (int k0 = 0; k0 < K; k0 += 32) {
    __syncthreads();                     // LDS reuse guard
#pragma unroll
    for (int i = 0; i < 2; ++i) {
      int c = i*256 + tid;               // 512 chunks of 16B per tile
      int row = c >> 2, off = (c & 3) * 8;
      gll16(&As[(i*256 + (wv<<6))*8], Ab + (size_t)row*K + k0 + off);
      gll16(&Bs[(i*256 + (wv<<6))*8], Bb + (size_t)row*K + k0 + off);
    }
    __syncthreads();                     // compiler emits vmcnt(0) drain here
    bhalf8 af[4], bfr[4];
#pragma unroll
    for (int rt = 0; rt < 4; ++rt)
      af[rt] = *(const bhalf8*)&As[(wm + rt*16 + l15)*32 + quad*8];
#pragma unroll
    for (int ct = 0; ct < 4; ++ct)
      bfr[ct] = *(const bhalf8*)&Bs[(wn + ct*16 + l15)*32 + quad*8];
#pragma unroll
    for (int rt = 0; rt < 4; ++rt)
#pragma unroll
      for (int ct = 0; ct < 4; ++ct)
        acc[rt][ct] = __builtin_amdgcn_mfma_f32_16x16x32_bf16(af[rt], bfr[ct], acc[rt][ct], 0, 0, 0);
  }

  if (MODE == 0) {
    float* Cf = (float*)Cout;
#pragma unroll
    for (int rt = 0; rt < 4; ++rt)
#pragma unroll
      for (int r = 0; r < 4; ++r) {
        int n = m0 + wm + rt*16 + quad*4 + r;
#pragma unroll
        for (int ct = 0; ct < 4; ++ct)
          Cf[(size_t)n * C_ + n0 + wn + ct*16 + l15] = acc[rt][ct][r];
      }
  } else {
    short* Cb = (short*)Cout;
#pragma unroll
    for (int rt = 0; rt < 4; ++rt)
#pragma unroll
      for (int r = 0; r < 4; ++r) {
        int n  = m0 + wm + rt*16 + quad*4 + r;
        int bb = n >> 11, t = n & (T_-1);
        int hh = (n0 + wn) >> 6;               // wave covers exactly one head
        size_t base = ((size_t)(bb*H_ + hh)*T_ + t)*DH_;
        if (MODE == 2) {
          float tf = (float)t;
#pragma unroll
          for (int ct = 0; ct < 2; ++ct) {
            int ii = ct*16 + l15;              // freq index 0..31
            // 10000^(-ii/32) = exp2(-ii * log2(1e4)/32)
            float ang = tf * exp2f((float)ii * (-0.4152410118609203f));
            float sn, cs;
            sincosf(ang, &sn, &cs);
            float xlo = acc[rt][ct][r], xhi = acc[rt][ct+2][r];
            Cb[base + ii]      = f2bf(xlo*cs - xhi*sn);   // j < 32: x1*c - x2*s
            Cb[base + ii + 32] = f2bf(xhi*cs + xlo*sn);   // j >=32: x2*c + x1*s
          }
        } else {
#pragma unroll
          for (int ct = 0; ct < 4; ++ct)
            Cb[base + ct*16 + l15] = f2bf(acc[rt][ct][r]);
        }
      }
  }
}

// One block per (b, h, 128 query rows). Causal decay retention + fused GroupNorm.
__global__ __launch_bounds__(256) void retention(
    const short* __restrict__ Qb, const short* __restrict__ Kb, const short* __restrict__ Vb,
    const float* __restrict__ gnw, const float* __restrict__ gnb,
    short* __restrict__ Xn)
{
  __shared__ __align__(16) short Qs[128*72];   // +8 pad: kills 16-way ds_read conflicts
  __shared__ __align__(16) short Ks[64*72];
  __shared__ __align__(16) short Vt[64*72];    // V transposed: Vt[d][l]
  __shared__ __align__(16) short Ss[128*72];   // wave-private S rows

  const int tid = threadIdx.x, lane = tid & 63, wv = tid >> 6;
  const int l15 = lane & 15, quad = lane >> 4;
  const int b = blockIdx.z, h = blockIdx.y, n0 = blockIdx.x << 7;
  const float log2g = log2f(1.f - exp2f(-5.f - (float)h));

  const short* Qg = Qb + ((size_t)(b*H_ + h)*T_ + n0) * DH_;
  const short* Kg = Kb + ((size_t)(b*H_ + h)*T_) * DH_;
  const short* Vg = Vb + ((size_t)(b*H_ + h)*T_) * DH_;

#pragma unroll
  for (int i = 0; i < 4; ++i) {                // stage Q tile 128x64
    int c = i*256 + tid, row = c >> 3, col = (c & 7) * 8;
    *(int4*)&Qs[row*72 + col] = *(const int4*)&Qg[row*64 + col];
  }

  floatx4 oacc[2][4] = {};
  const int wrow = wv * 32;                    // wave owns 32 S/O rows
  const int mtmax = (n0 + 127) >> 6;
  for (int mt = 0; mt <= mtmax; ++mt) {
    const int m0 = mt << 6;
    int dmin = n0 - (m0 + 63);
    if (dmin > 0 && log2g * (float)dmin < -34.f) continue;  // block-uniform skip
    __syncthreads();                           // K/V (and first-iter Q) ready guard
#pragma unroll
    for (int i = 0; i < 2; ++i) {              // stage K tile + V tile (transposed)
      int c = i*256 + tid, row = c >> 3, col = (c & 7) * 8;
      *(int4*)&Ks[row*72 + col] = *(const int4*)&Kg[(size_t)(m0 + row)*64 + col];
      union { int4 v; short s[8]; } u;
      u.v = *(const int4*)&Vg[(size_t)(m0 + row)*64 + col];
#pragma unroll
      for (int j = 0; j < 8; ++j) Vt[(col + j)*72 + row] = u.s[j];
    }
    __syncthreads();

    floatx4 sacc[2][4] = {};
#pragma unroll
    for (int ks = 0; ks < 2; ++ks) {           // S = Q @ K^T  (DH=64 -> 2 k-steps)
      bhalf8 aq[2], bk[4];
#pragma unroll
      for (int rt = 0; rt < 2; ++rt)
        aq[rt] = *(const bhalf8*)&Qs[(wrow + rt*16 + l15)*72 + ks*32 + quad*8];
#pragma unroll
      for (int ct = 0; ct < 4; ++ct)
        bk[ct] = *(const bhalf8*)&Ks[(ct*16 + l15)*72 + ks*32 + quad*8];
#pragma unroll
      for (int rt = 0; rt < 2; ++rt)
#pragma unroll
        for (int ct = 0; ct < 4; ++ct)
          sacc[rt][ct] = __builtin_amdgcn_mfma_f32_16x16x32_bf16(aq[rt], bk[ct], sacc[rt][ct], 0, 0, 0);
    }

    // decay * mask * 1/sqrt(DH), fp32 -> bf16, C/D layout -> LDS (A layout source)
#pragma unroll
    for (int rt = 0; rt < 2; ++rt) {
      int nrow = n0 + wrow + rt*16 + quad*4;
#pragma unroll
      for (int ct = 0; ct < 4; ++ct) {
        int m = m0 + ct*16 + l15;
#pragma unroll
        for (int r = 0; r < 4; ++r) {
          int dist = nrow + r - m;
          float dec = (dist >= 0) ? exp2f(log2g * (float)dist) * 0.125f : 0.f;
          Ss[(wrow + rt*16 + quad*4 + r)*72 + ct*16 + l15] = f2bf(sacc[rt][ct][r] * dec);
        }
      }
    }
    // no barrier: each wave reads back only its own 32 Ss rows (intra-wave lgkmcnt order)

#pragma unroll
    for (int ks = 0; ks < 2; ++ks) {           // O += S @ V
      bhalf8 as_[2], bv[4];
#pragma unroll
      for (int rt = 0; rt < 2; ++rt)
        as_[rt] = *(const bhalf8*)&Ss[(wrow + rt*16 + l15)*72 + ks*32 + quad*8];
#pragma unroll
      for (int ct = 0; ct < 4; ++ct)
        bv[ct] = *(const bhalf8*)&Vt[(ct*16 + l15)*72 + ks*32 + quad*8];
#pragma unroll
      for (int rt = 0; rt < 2; ++rt)
#pragma unroll
        for (int ct = 0; ct < 4; ++ct)
          oacc[rt][ct] = __builtin_amdgcn_mfma_f32_16x16x32_bf16(as_[rt], bv[ct], oacc[rt][ct], 0, 0, 0);
    }
  }

  // fused GroupNorm over DH (row = one quad's 16 lanes x 4 ct), write (B,T,C) bf16
#pragma unroll
  for (int rt = 0; rt < 2; ++rt)
#pragma unroll
    for (int r = 0; r < 4; ++r) {
      float s1 = oacc[rt][0][r] + oacc[rt][1][r] + oacc[rt][2][r] + oacc[rt][3][r];
      float s2 = oacc[rt][0][r]*oacc[rt][0][r] + oacc[rt][1][r]*oacc[rt][1][r]
               + oacc[rt][2][r]*oacc[rt][2][r] + oacc[rt][3][r]*oacc[rt][3][r];
#pragma unroll
      for (int off = 1; off < 16; off <<= 1) {
        s1 += __shfl_xor(s1, off);
        s2 += __shfl_xor(s2, off);
      }
      float mean = s1 * (1.f/64.f);
      float var  = s2 * (1.f/64.f) - mean*mean;
      float rstd = rsqrtf(var + 1e-5f);
      int t = n0 + wrow + rt*16 + quad*4 + r;
      size_t obase = ((size_t)b*T_ + t)*C_ + h*DH_;
#pragma unroll
      for (int ct = 0; ct < 4; ++ct) {
        int d = ct*16 + l15;
        float y = (oacc[rt][ct][r] - mean)*rstd*gnw[h*DH_ + d] + gnb[h*DH_ + d];
        Xn[obase + d] = f2bf(y);
      }
    }
}

extern "C" void kernel_launch(void* const* d_in, const int* in_sizes, int n_in,
                              void* d_out, int out_size, void* d_ws, size_t ws_size,
                              hipStream_t stream) {
  (void)in_sizes; (void)n_in; (void)out_size; (void)ws_size;
  const float* x   = (const float*)d_in[0];
  const float* Wq  = (const float*)d_in[1];
  const float* Wk  = (const float*)d_in[2];
  const float* Wv  = (const float*)d_in[3];
  const float* Wo  = (const float*)d_in[4];
  const float* gnw = (const float*)d_in[5];
  const float* gnb = (const float*)d_in[6];
  float* out = (float*)d_out;

  char* ws = (char*)d_ws;                 // 48 MB used
  short* Xb  = (short*)(ws);              // x bf16:  4096x1024 (8 MB)
  short* Wqb = (short*)(ws + (8u<<20));   // 2 MB each
  short* Wkb = (short*)(ws + (10u<<20));
  short* Wvb = (short*)(ws + (12u<<20));
  short* Wob = (short*)(ws + (14u<<20));
  short* Qb  = (short*)(ws + (16u<<20));  // (B,H,T,DH) bf16, 8 MB each
  short* Kb  = (short*)(ws + (24u<<20));
  short* Vb  = (short*)(ws + (32u<<20));
  short* Xn  = (short*)(ws + (40u<<20));  // normalized retention out (B,T,C) bf16

  cvt_bf16<<<(M_*C_/4 + 255)/256, 256, 0, stream>>>(x,  Xb,  M_*C_/4);
  cvt_bf16<<<(C_*C_/4 + 255)/256, 256, 0, stream>>>(Wq, Wqb, C_*C_/4);
  cvt_bf16<<<(C_*C_/4 + 255)/256, 256, 0, stream>>>(Wk, Wkb, C_*C_/4);
  cvt_bf16<<<(C_*C_/4 + 255)/256, 256, 0, stream>>>(Wv, Wvb, C_*C_/4);
  cvt_bf16<<<(C_*C_/4 + 255)/256, 256, 0, stream>>>(Wo, Wob, C_*C_/4);

  dim3 gg(C_/128, M_/128);
  gemm_bt<2><<<gg, 256, 0, stream>>>(Xb, Wqb, Qb);   // Q with RoPE
  gemm_bt<2><<<gg, 256, 0, stream>>>(Xb, Wkb, Kb);   // K with RoPE
  gemm_bt<1><<<gg, 256, 0, stream>>>(Xb, Wvb, Vb);   // V plain
  retention<<<dim3(T_/128, H_, B_), 256, 0, stream>>>(Qb, Kb, Vb, gnw, gnb, Xn);
  gemm_bt<0><<<gg, 256, 0, stream>>>(Xn, Wob, (void*)out);
}